// Round 9
// baseline (287.447 us; speedup 1.0000x reference)
//
#include <hip/hip_runtime.h>

typedef unsigned int u32;
typedef unsigned short u16;
typedef _Float16 h2 __attribute__((ext_vector_type(2)));
typedef _Float16 h4 __attribute__((ext_vector_type(4)));
typedef float f4 __attribute__((ext_vector_type(4)));

#define B_ 64
#define N_ 8192
#define DI 8
#define O_ 10
#define DO_ 16
#define OD 160          // O_*DO_
#define NB2 512         // fused grid: 2 blocks/CU (LDS 77.5 KB -> exactly 2 fit)
#define NCH 16          // n per block: 512*16 = 8192
#define WROW (OD * DI)  // 1280 elems per n
#define WLN (NCH * WROW)// 20480 f16 = 40960 B
#define XROWH 136       // x row per b (f16): 16n*8 + 8 pad -> 272 B stride
#define CSTRH 164       // f16 combine row stride: 328 B -> 2-way banks max

// ---- fallback (R16 proven) params ----
#define NCHUNK 8
#define CHN 2
#define NCHK (NCHUNK / CHN)
#define CHH (CHN * WROW)

// cvt_pkrtz returns __fp16-vec2; bit_cast to our _Float16-vec2 (same bits).
static __device__ __forceinline__ h2 pkrtz(float a, float b) {
    return __builtin_bit_cast(h2, __builtin_amdgcn_cvt_pkrtz(a, b));
}

// Packed-f16 sum across the four 16-lane rows, replicated to all lanes --
// PROVEN R13 chain (ds_swizzle xor^16 + ds_bpermute xor^32). permlane swaps
// are NOT equivalent (R14/R15 evidence); do not substitute.
static __device__ __forceinline__ h2 hsum4(h2 v, int a32) {
    int pi = __builtin_bit_cast(int, v);
    h2 pk = v + __builtin_bit_cast(h2, __builtin_amdgcn_ds_swizzle(pi, 0x401F));
    pi = __builtin_bit_cast(int, pk);
    pk = pk + __builtin_bit_cast(h2, __builtin_amdgcn_ds_bpermute(a32, pi));
    return pk;
}

// R20 tree barrier. R19's flat counter = 256 serialized cross-XCD RMWs on one
// line (~30us/barrier at 512 blocks it would be worse). Tree: 8 leaf lines
// (bid&7 ~ XCD under round-robin dispatch -> leaf RMWs are mostly L2-local),
// leaf completer bumps root (8 RMWs), root completer sets flag. Waiters poll
// flag RELAXED (no cache ops) then ONE ACQUIRE load per block (L1 shared by
// the whole block). Release chain: block writes -> leaf RMW(REL) -> root
// RMW(REL) -> flag store(REL); all same-address RMW chains => transitive.
static __device__ __forceinline__ void gbar_arrive(u32* bar, u32 k) {
    __syncthreads();
    if (threadIdx.x == 0) {
        u32* leaf = bar + (blockIdx.x & 7) * 32;     // 128-B separated lines
        u32* root = bar + 8 * 32;
        u32* flag = bar + 9 * 32;
        const u32 lo = __hip_atomic_fetch_add(leaf, 1u, __ATOMIC_RELEASE,
                                              __HIP_MEMORY_SCOPE_AGENT);
        if (lo == k * (NB2 / 8) - 1) {
            const u32 ro = __hip_atomic_fetch_add(root, 1u, __ATOMIC_RELEASE,
                                                  __HIP_MEMORY_SCOPE_AGENT);
            if (ro == k * 8 - 1)
                __hip_atomic_store(flag, k, __ATOMIC_RELEASE, __HIP_MEMORY_SCOPE_AGENT);
        }
    }
}
static __device__ __forceinline__ void gbar_wait(u32* bar, u32 k) {
    if (threadIdx.x == 0) {
        u32* flag = bar + 9 * 32;
        while (__hip_atomic_load(flag, __ATOMIC_RELAXED, __HIP_MEMORY_SCOPE_AGENT) < k)
            __builtin_amdgcn_s_sleep(8);
        (void)__hip_atomic_load(flag, __ATOMIC_ACQUIRE, __HIP_MEMORY_SCOPE_AGENT);
    }
    __syncthreads();
}

// R20 = R19 fused persistent kernel at 2 blocks/CU. R19 was latency-bound
// (VALU 18%, Mfma 4.7%) at 1 block/CU = 2 waves/SIMD; NCH=16 + f16 combine
// buffer shrinks LDS to 77.5 KB -> 2 blocks/CU = 4 waves/SIMD (double hiding
// for the softmax DS/exp chains) + tree barrier. Traffic design unchanged
// (W+x staged once; 3 rounds from LDS; fp16 partials; 64 in-kernel reducers).
__global__ __launch_bounds__(512, 4)
void caps_fused(const float* __restrict__ Xf, const float* __restrict__ Wf,
                u32* bar, float* __restrict__ V0f, u16* __restrict__ Vb,
                _Float16* __restrict__ P, float* __restrict__ out) {
    __shared__ _Float16 wl[WLN];                         // 40960 B
    __shared__ _Float16 xl[B_ * XROWH];                  // 17408 B
    __shared__ alignas(16) _Float16 cmbh[B_ * CSTRH];    // 20992 B -> 79360 total

    const int tid  = threadIdx.x;
    const int lane = tid & 63;
    const int c    = lane & 15;
    const int hh   = lane >> 4;
    const int w    = __builtin_amdgcn_readfirstlane(tid >> 6);
    const int tau  = w & 3, eta = w >> 2;
    const int b    = tau * 16 + c;
    const int bid  = blockIdx.x;
    const int nb   = bid * NCH;
    const int a32  = (lane ^ 32) << 2;
    const int ioff = (hh < 2) ? 4 * hh : 0;

    // ---- stage W + x (issue all loads first, then convert+write) ----
    {
        const float* src = Wf + (size_t)nb * WROW;       // 5120 float4 / 512 thr
        float4 wv[10];
        #pragma unroll
        for (int k = 0; k < 10; ++k) wv[k] = *(const float4*)(src + (tid + k * 512) * 4);
        const float* xs = Xf + ((size_t)(tid >> 3) * N_ + nb) * DI;
        float4 xv[4];                                    // 32 float4 per b-row / 8 thr
        #pragma unroll
        for (int k = 0; k < 4; ++k) xv[k] = *(const float4*)(xs + ((tid & 7) + k * 8) * 4);
        #pragma unroll
        for (int k = 0; k < 10; ++k) {
            h2 lo = pkrtz(wv[k].x, wv[k].y), hi = pkrtz(wv[k].z, wv[k].w);
            h4 hv; hv[0] = lo[0]; hv[1] = lo[1]; hv[2] = hi[0]; hv[3] = hi[1];
            *(h4*)&wl[(tid + k * 512) * 4] = hv;
        }
        #pragma unroll
        for (int k = 0; k < 4; ++k) {
            const int idx = ((tid & 7) + k * 8) * 4;     // f16 pos in 128-el row
            h2 lo = pkrtz(xv[k].x, xv[k].y), hi = pkrtz(xv[k].z, xv[k].w);
            h4 hv; hv[0] = lo[0]; hv[1] = lo[1]; hv[2] = hi[0]; hv[3] = hi[1];
            *(h4*)&xl[(tid >> 3) * XROWH + idx] = hv;
        }
    }
    __syncthreads();

    const f4 fz = {0.f, 0.f, 0.f, 0.f};
    f4 acc[O_], vv[O_];
    const _Float16* xrow = xl + b * XROWH + ioff;

    auto loadvv = [&]() {
        const _Float16* vp = (const _Float16*)Vb + (size_t)b * OD + 4 * hh;
        #pragma unroll
        for (int oo = 0; oo < O_; ++oo) {
            const h4 hv = *(const h4*)(vp + oo * DO_);
            vv[oo][0] = (float)hv[0]; vv[oo][1] = (float)hv[1];
            vv[oo][2] = (float)hv[2]; vv[oo][3] = (float)hv[3];
        }
    };

    auto step1 = [&](int sn) {
        h4 bf = {(_Float16)0.f, (_Float16)0.f, (_Float16)0.f, (_Float16)0.f};
        if (hh < 2) bf = *(const h4*)(xrow + sn * 8);
        const _Float16* wr = wl + sn * WROW + c * DI + ioff;
        f4 u[O_];
        #pragma unroll
        for (int oo = 0; oo < O_; ++oo) {
            h4 af = {(_Float16)0.f, (_Float16)0.f, (_Float16)0.f, (_Float16)0.f};
            if (hh < 2) af = *(const h4*)(wr + oo * (DO_ * DI));
            u[oo] = __builtin_amdgcn_mfma_f32_16x16x16f16(af, bf, fz, 0, 0, 0);
        }
        float tex[O_];
        #pragma unroll
        for (int q = 0; q < 5; ++q) {
            const int o0 = 2 * q, o1 = 2 * q + 1;
            const float p0 = u[o0][0]*vv[o0][0] + u[o0][1]*vv[o0][1]
                           + u[o0][2]*vv[o0][2] + u[o0][3]*vv[o0][3];
            const float p1 = u[o1][0]*vv[o1][0] + u[o1][1]*vv[o1][1]
                           + u[o1][2]*vv[o1][2] + u[o1][3]*vv[o1][3];
            const h2 pk = hsum4(pkrtz(p0, p1), a32);
            tex[o0] = __expf((float)pk[0]);
            tex[o1] = __expf((float)pk[1]);
        }
        const float den = (((tex[0] + tex[1]) + (tex[2] + tex[3]))
                         + ((tex[4] + tex[5]) + (tex[6] + tex[7])))
                         + (tex[8] + tex[9]);
        const float rinv = 1.0f / den;
        #pragma unroll
        for (int oo = 0; oo < O_; ++oo) {
            const float co = tex[oo] * rinv;
            acc[oo][0] = fmaf(co, u[oo][0], acc[oo][0]);
            acc[oo][1] = fmaf(co, u[oo][1], acc[oo][1]);
            acc[oo][2] = fmaf(co, u[oo][2], acc[oo][2]);
            acc[oo][3] = fmaf(co, u[oo][3], acc[oo][3]);
        }
    };

    // eta-combine parked as f16 (partials ~0.01 mag; f16 noise ~5e-6 -- far
    // under threshold margin), then per-block fp16 partial write.
    auto epi = [&](float sc) {
        if (eta == 1) {
            #pragma unroll
            for (int oo = 0; oo < O_; ++oo) {
                h4 hp;
                hp[0] = (_Float16)acc[oo][0]; hp[1] = (_Float16)acc[oo][1];
                hp[2] = (_Float16)acc[oo][2]; hp[3] = (_Float16)acc[oo][3];
                *(h4*)&cmbh[b * CSTRH + oo * DO_ + 4 * hh] = hp;
            }
        }
        __syncthreads();
        if (eta == 0) {
            _Float16* my = P + (size_t)bid * (B_ * OD) + (size_t)b * OD;
            #pragma unroll
            for (int oo = 0; oo < O_; ++oo) {
                const h4 hp = *(const h4*)&cmbh[b * CSTRH + oo * DO_ + 4 * hh];
                h4 hq;
                hq[0] = (_Float16)(sc * (acc[oo][0] + (float)hp[0]));
                hq[1] = (_Float16)(sc * (acc[oo][1] + (float)hp[1]));
                hq[2] = (_Float16)(sc * (acc[oo][2] + (float)hp[2]));
                hq[3] = (_Float16)(sc * (acc[oo][3] + (float)hp[3]));
                *(h4*)(my + oo * DO_ + 4 * hh) = hq;
            }
        }
        __syncthreads();   // cmbh reusable next round
    };

    // in-kernel cross-block reduce + squash for batch b0 = bid (blocks 0..63);
    // scratch overlays cmbh (combine values already consumed).
    auto reduceF = [&](int r) {
        float* sg  = (float*)cmbh;          // 480 f32
        float* ss  = (float*)cmbh + 512;    // 160 f32
        float* sca = (float*)cmbh + 704;    // 16 f32
        if (tid < 480) {
            const int g = tid / 160, od = tid - g * 160;
            float a2 = 0.0f;
            const _Float16* p0 = P + (size_t)bid * OD + od;
            #pragma unroll 16
            for (int p = g; p < NB2; p += 3)
                a2 += (float)p0[(size_t)p * (B_ * OD)];
            sg[g * 160 + od] = a2;
        }
        __syncthreads();
        if (tid < 160) ss[tid] = sg[tid] + sg[160 + tid] + sg[320 + tid];
        __syncthreads();
        if (tid < 16) {
            float nrm = 0.0f;
            #pragma unroll
            for (int o = 0; o < O_; ++o) { const float x = ss[o * DO_ + tid]; nrm = fmaf(x, x, nrm); }
            sca[tid] = nrm / (1.0f + nrm) * rsqrtf(nrm + 1e-9f);
        }
        __syncthreads();
        if (tid < 160) {
            const float v = ss[tid] * sca[tid & 15];
            const int idx = bid * OD + tid;
            if (r == 0) {
                V0f[idx] = v;
                _Float16 hcv = (_Float16)v;
                Vb[idx] = __builtin_bit_cast(u16, hcv);
            } else if (r == 1) {
                _Float16 hcv = (_Float16)(V0f[idx] + v);
                Vb[idx] = __builtin_bit_cast(u16, hcv);
            } else {
                out[idx] = v;
            }
        }
        __syncthreads();
    };

    // ---- round 0: uniform c = 0.1, chain through MFMA C ----
    #pragma unroll
    for (int oo = 0; oo < O_; ++oo) acc[oo] = fz;
    #pragma unroll 1
    for (int st = 0; st < NCH / 2; ++st) {
        const int sn = eta * (NCH / 2) + st;
        h4 bf = {(_Float16)0.f, (_Float16)0.f, (_Float16)0.f, (_Float16)0.f};
        if (hh < 2) bf = *(const h4*)(xrow + sn * 8);
        const _Float16* wr = wl + sn * WROW + c * DI + ioff;
        #pragma unroll
        for (int oo = 0; oo < O_; ++oo) {
            h4 af = {(_Float16)0.f, (_Float16)0.f, (_Float16)0.f, (_Float16)0.f};
            if (hh < 2) af = *(const h4*)(wr + oo * (DO_ * DI));
            acc[oo] = __builtin_amdgcn_mfma_f32_16x16x16f16(af, bf, acc[oo], 0, 0, 0);
        }
    }
    epi(0.1f);
    gbar_arrive(bar, 1); gbar_wait(bar, 1);
    if (bid < B_) reduceF(0);
    gbar_arrive(bar, 2); gbar_wait(bar, 2);
    loadvv();

    // ---- round 1 ----
    #pragma unroll
    for (int oo = 0; oo < O_; ++oo) acc[oo] = fz;
    #pragma unroll 1
    for (int st = 0; st < NCH / 2; ++st) step1(eta * (NCH / 2) + st);
    epi(1.0f);
    gbar_arrive(bar, 3); gbar_wait(bar, 3);
    if (bid < B_) reduceF(1);
    gbar_arrive(bar, 4); gbar_wait(bar, 4);
    loadvv();

    // ---- round 2 ----
    #pragma unroll
    for (int oo = 0; oo < O_; ++oo) acc[oo] = fz;
    #pragma unroll 1
    for (int st = 0; st < NCH / 2; ++st) step1(eta * (NCH / 2) + st);
    epi(1.0f);

    // final: everyone arrives; only reducer blocks wait and finish
    gbar_arrive(bar, 5);
    if (bid < B_) {
        gbar_wait(bar, 5);
        reduceF(2);
    }
}

// ================= fallback path (R16 proven, atomic accumulator) =========
template <int PHASE, int TAIL>
__global__ __launch_bounds__(256, 3)
void caps_pass(const float* __restrict__ Xf, const float* __restrict__ Wf,
               const u16* __restrict__ Vb, float* __restrict__ Sout,
               _Float16* __restrict__ Sh) {
    __shared__ _Float16 stage[2 * CHH];

    const int tid  = threadIdx.x;
    const int lane = tid & 63;
    const int c    = lane & 15;
    const int hh   = lane >> 4;
    const int tau  = __builtin_amdgcn_readfirstlane(tid >> 6);
    const int b    = tau * 16 + c;
    const int nb   = blockIdx.x * NCHUNK;
    const int a32  = (lane ^ 32) << 2;

    int off[5];
    #pragma unroll
    for (int k = 0; k < 5; ++k) off[k] = (tid + k * 256) * 2;

    float2 st[5];
    {
        const float* src = Wf + (size_t)nb * WROW;
        #pragma unroll
        for (int k = 0; k < 5; ++k) st[k] = *(const float2*)(src + off[k]);
        #pragma unroll
        for (int k = 0; k < 5; ++k)
            *(h2*)&stage[off[k]] = pkrtz(st[k].x, st[k].y);
    }

    f4 vv[O_];
    if (PHASE > 0) {
        const _Float16* vp = (const _Float16*)Vb + (size_t)b * OD + 4 * hh;
        #pragma unroll
        for (int oo = 0; oo < O_; ++oo) {
            const h4 hv = *(const h4*)(vp + oo * DO_);
            vv[oo][0] = (float)hv[0]; vv[oo][1] = (float)hv[1];
            vv[oo][2] = (float)hv[2]; vv[oo][3] = (float)hv[3];
        }
    }

    const f4 fz = {0.f, 0.f, 0.f, 0.f};
    f4 acc[O_];
    #pragma unroll
    for (int oo = 0; oo < O_; ++oo) acc[oo] = fz;

    const int ioff = (hh < 2) ? 4 * hh : 0;
    const float* xb = Xf + ((size_t)b * N_ + nb) * DI + ioff;
    float4 xcur = *(const float4*)xb;

    __syncthreads();

    #pragma unroll 1
    for (int ch = 0; ch < NCHK; ++ch) {
        if (ch < NCHK - 1) {
            const float* src = Wf + (size_t)(nb + (ch + 1) * CHN) * WROW;
            #pragma unroll
            for (int k = 0; k < 5; ++k) st[k] = *(const float2*)(src + off[k]);
        }
        const _Float16* wb = stage + (ch & 1) * CHH;

        #pragma unroll
        for (int kk = 0; kk < CHN; ++kk) {
            const int s = ch * CHN + kk;
            float4 xnext = xcur;
            if (s < NCHUNK - 1)
                xnext = *(const float4*)(xb + (size_t)(s + 1) * DI);

            h4 bf = {(_Float16)0.f, (_Float16)0.f, (_Float16)0.f, (_Float16)0.f};
            if (hh < 2) {
                const h2 lo = pkrtz(xcur.x, xcur.y);
                const h2 hi = pkrtz(xcur.z, xcur.w);
                bf[0] = lo[0]; bf[1] = lo[1]; bf[2] = hi[0]; bf[3] = hi[1];
            }
            xcur = xnext;

            const _Float16* wr = wb + kk * WROW + c * DI + ioff;
            f4 u[O_];
            #pragma unroll
            for (int oo = 0; oo < O_; ++oo) {
                h4 af = {(_Float16)0.f, (_Float16)0.f, (_Float16)0.f, (_Float16)0.f};
                if (hh < 2) af = *(const h4*)(wr + oo * (DO_ * DI));
                if (PHASE == 0) {
                    acc[oo] = __builtin_amdgcn_mfma_f32_16x16x16f16(af, bf, acc[oo], 0, 0, 0);
                } else {
                    u[oo] = __builtin_amdgcn_mfma_f32_16x16x16f16(af, bf, fz, 0, 0, 0);
                }
            }

            if (PHASE > 0) {
                float tex[O_];
                #pragma unroll
                for (int q = 0; q < 5; ++q) {
                    const int o0 = 2 * q, o1 = 2 * q + 1;
                    const float p0 = u[o0][0]*vv[o0][0] + u[o0][1]*vv[o0][1]
                                   + u[o0][2]*vv[o0][2] + u[o0][3]*vv[o0][3];
                    const float p1 = u[o1][0]*vv[o1][0] + u[o1][1]*vv[o1][1]
                                   + u[o1][2]*vv[o1][2] + u[o1][3]*vv[o1][3];
                    const h2 pk = hsum4(pkrtz(p0, p1), a32);
                    tex[o0] = __expf((float)pk[0]);
                    tex[o1] = __expf((float)pk[1]);
                }
                const float den = (((tex[0] + tex[1]) + (tex[2] + tex[3]))
                                 + ((tex[4] + tex[5]) + (tex[6] + tex[7])))
                                 + (tex[8] + tex[9]);
                const float rinv = 1.0f / den;
                #pragma unroll
                for (int oo = 0; oo < O_; ++oo) {
                    const float co = tex[oo] * rinv;
                    acc[oo][0] = fmaf(co, u[oo][0], acc[oo][0]);
                    acc[oo][1] = fmaf(co, u[oo][1], acc[oo][1]);
                    acc[oo][2] = fmaf(co, u[oo][2], acc[oo][2]);
                    acc[oo][3] = fmaf(co, u[oo][3], acc[oo][3]);
                }
            }
        }

        if (ch < NCHK - 1) {
            _Float16* dst = stage + ((ch + 1) & 1) * CHH;
            #pragma unroll
            for (int k = 0; k < 5; ++k)
                *(h2*)&dst[off[k]] = pkrtz(st[k].x, st[k].y);
        }
        __syncthreads();
    }

    const float sc = (PHASE == 0) ? 0.1f : 1.0f;
    {
        float* Sg = Sout + (size_t)b * OD;
        #pragma unroll
        for (int oo = 0; oo < O_; ++oo) {
            atomicAdd(&Sg[oo * DO_ + 4 * hh + 0], sc * acc[oo][0]);
            atomicAdd(&Sg[oo * DO_ + 4 * hh + 1], sc * acc[oo][1]);
            atomicAdd(&Sg[oo * DO_ + 4 * hh + 2], sc * acc[oo][2]);
            atomicAdd(&Sg[oo * DO_ + 4 * hh + 3], sc * acc[oo][3]);
        }
    }
    (void)Sh;
}

template <int PHASE>
__global__ __launch_bounds__(1024)
void caps_finalize(float* __restrict__ S, float* __restrict__ V0f,
                   u16* __restrict__ Vb, float* __restrict__ out) {
    const int tid = threadIdx.x;
    const int b = tid >> 4, d = tid & 15;
    float sv[O_];
    float norm = 0.0f;
    #pragma unroll
    for (int o = 0; o < O_; ++o) {
        sv[o] = S[b * OD + o * DO_ + d];
        norm = fmaf(sv[o], sv[o], norm);
    }
    const float scale = norm / (1.0f + norm) * rsqrtf(norm + 1e-9f);
    #pragma unroll
    for (int o = 0; o < O_; ++o) {
        const int idx = b * OD + o * DO_ + d;
        const float v = scale * sv[o];
        if (PHASE == 0) {
            V0f[idx] = v;
            _Float16 hcv = (_Float16)v;
            Vb[idx] = __builtin_bit_cast(u16, hcv);
            S[idx] = 0.0f;
        } else if (PHASE == 1) {
            _Float16 hcv = (_Float16)(V0f[idx] + v);
            Vb[idx] = __builtin_bit_cast(u16, hcv);
            S[idx] = 0.0f;
        } else {
            out[idx] = v;
        }
    }
}

extern "C" void kernel_launch(void* const* d_in, const int* in_sizes, int n_in,
                              void* d_out, int out_size, void* d_ws, size_t ws_size,
                              hipStream_t stream) {
    const float* Xf = (const float*)d_in[0];   // x: [64, 8192, 8] fp32
    const float* Wf = (const float*)d_in[1];   // W: [1, 8192, 10, 16, 8] fp32
    float* out = (float*)d_out;

    const size_t velems = (size_t)B_ * OD;                 // 10240
    float* V0f = (float*)d_ws;                             // 40960 B
    u16* Vb = (u16*)(V0f + velems);                        // 20480 B -> ends 61440
    u32* bar = (u32*)((char*)d_ws + 61440);                // 1280 B: 8 leaf+root+flag
    const size_t pbase = 62720;
    const size_t need = pbase + (size_t)NB2 * velems * 2;  // ~10.5 MB

    if (ws_size >= need) {
        _Float16* P = (_Float16*)((char*)d_ws + pbase);
        (void)hipMemsetAsync(bar, 0, 1280, stream);
        caps_fused<<<dim3(NB2), dim3(512), 0, stream>>>(Xf, Wf, bar, V0f, Vb, P, out);
    } else {
        // fallback: global atomic accumulator (R16 proven path)
        float* S = (float*)((char*)d_ws + pbase);
        const dim3 grid(N_ / NCHUNK), blk(256), one(1), fblk(1024);
        (void)hipMemsetAsync(S, 0, velems * sizeof(float), stream);
        caps_pass<0, 2><<<grid, blk, 0, stream>>>(Xf, Wf, nullptr, S, nullptr);
        caps_finalize<0><<<one, fblk, 0, stream>>>(S, V0f, Vb, nullptr);
        caps_pass<1, 2><<<grid, blk, 0, stream>>>(Xf, Wf, Vb, S, nullptr);
        caps_finalize<1><<<one, fblk, 0, stream>>>(S, V0f, Vb, nullptr);
        caps_pass<1, 2><<<grid, blk, 0, stream>>>(Xf, Wf, Vb, S, nullptr);
        caps_finalize<2><<<one, fblk, 0, stream>>>(S, nullptr, nullptr, out);
    }
}